// Round 1
// baseline (303.272 us; speedup 1.0000x reference)
//
#include <hip/hip_runtime.h>

typedef __attribute__((ext_vector_type(8))) short bf16x8;
typedef __attribute__((ext_vector_type(4))) float f32x4;

#define HH 768   // hidden
#define EE 768   // embed
#define BB 32
#define SS 512
#define PP 76
#define KCAND 64
#define MM (BB * PP)  // 2432

// round-to-nearest-even fp32 -> bf16 bit pattern
__device__ inline unsigned short f2bf(float f) {
    unsigned int u = __float_as_uint(f);
    u += 0x7fffu + ((u >> 16) & 1u);
    return (unsigned short)(u >> 16);
}

// Pass 0: Wt[e][h] = bf16(W[h][e])  (transpose + convert, LDS-tiled)
__global__ __launch_bounds__(256) void prep_w_kernel(
    const float* __restrict__ W, unsigned short* __restrict__ Wt) {
    __shared__ float tile[32][33];
    const int h0 = blockIdx.x * 32, e0 = blockIdx.y * 32;
    const int c = threadIdx.x & 31, r = threadIdx.x >> 5;  // r: 0..7
#pragma unroll
    for (int rr = r; rr < 32; rr += 8)
        tile[rr][c] = W[(size_t)(h0 + rr) * EE + e0 + c];
    __syncthreads();
#pragma unroll
    for (int rr = r; rr < 32; rr += 8)
        Wt[(size_t)(e0 + rr) * HH + h0 + c] = f2bf(tile[c][rr]);
}

// Pass 1: lm_raw[m][e] = sum_h seq[b, pos[b,p], h] * W[h][e]
// Fused gather (indirect A rows) + bf16 MFMA GEMM. Tile 64x64, BK=64.
__global__ __launch_bounds__(256) void gemm_kernel(
    const float* __restrict__ seq, const int* __restrict__ mpos,
    const unsigned short* __restrict__ Wt, float* __restrict__ lm) {
    // +8 ushort pad (16B) keeps b128 alignment and spreads banks (2-way = free)
    __shared__ unsigned short Alds[64][72];
    __shared__ unsigned short Blds[64][72];
    const int bm = blockIdx.y, bn = blockIdx.x;
    const int tid = threadIdx.x;
    const int r = tid >> 2, q = tid & 3;  // staging: row 0..63, quarter 0..3

    // A source row (constant across K loop)
    const int gm = bm * 64 + r;
    const int b = gm / PP;
    const int p = gm - b * PP;
    const int ps = mpos[b * PP + p];
    const float* srow = seq + (size_t)(b * SS + ps) * HH;
    const unsigned short* wrow = Wt + (size_t)(bn * 64 + r) * HH;

    const int lane = tid & 63, wv = tid >> 6;
    const int wm = wv >> 1, wn = wv & 1;  // 2x2 wave grid, each wave 32x32
    f32x4 acc[2][2] = {};

    for (int kk = 0; kk < HH; kk += 64) {
        __syncthreads();
        // stage A: 64 rows x 64 k, fp32 -> bf16 in-register
#pragma unroll
        for (int j = 0; j < 4; ++j) {
            float4 v = *(const float4*)(srow + kk + q * 16 + j * 4);
            ushort4 s;
            s.x = f2bf(v.x); s.y = f2bf(v.y); s.z = f2bf(v.z); s.w = f2bf(v.w);
            *(ushort4*)&Alds[r][q * 16 + j * 4] = s;
        }
        // stage B (already bf16, already [n][k] layout): 16B vector copies
#pragma unroll
        for (int j = 0; j < 2; ++j) {
            int4 w = *(const int4*)(wrow + kk + q * 16 + j * 8);
            *(int4*)&Blds[r][q * 16 + j * 8] = w;
        }
        __syncthreads();
#pragma unroll
        for (int ks = 0; ks < 64; ks += 32) {
            bf16x8 af[2], bfr[2];
#pragma unroll
            for (int t = 0; t < 2; ++t)
                af[t] = *(const bf16x8*)&Alds[wm * 32 + t * 16 + (lane & 15)]
                                             [ks + (lane >> 4) * 8];
#pragma unroll
            for (int t = 0; t < 2; ++t)
                bfr[t] = *(const bf16x8*)&Blds[wn * 32 + t * 16 + (lane & 15)]
                                              [ks + (lane >> 4) * 8];
#pragma unroll
            for (int tm = 0; tm < 2; ++tm)
#pragma unroll
                for (int tn = 0; tn < 2; ++tn)
                    acc[tm][tn] = __builtin_amdgcn_mfma_f32_16x16x32_bf16(
                        af[tm], bfr[tn], acc[tm][tn], 0, 0, 0);
        }
    }
    // epilogue: C/D layout col=lane&15, row=(lane>>4)*4+reg  [verified m89/m91]
#pragma unroll
    for (int tm = 0; tm < 2; ++tm)
#pragma unroll
        for (int tn = 0; tn < 2; ++tn) {
            const int col = bn * 64 + wn * 32 + tn * 16 + (lane & 15);
            const int rbase = bm * 64 + wm * 32 + tm * 16 + (lane >> 4) * 4;
#pragma unroll
            for (int g = 0; g < 4; ++g)
                lm[(size_t)(rbase + g) * EE + col] = acc[tm][tn][g];
        }
}

// Pass 2: bias + LayerNorm (fused) + candidate dot products.
// One block per (b,p); wave per candidate; lm row cached in 12 regs/lane.
__global__ __launch_bounds__(256) void logits_kernel(
    const float* __restrict__ lm, const float* __restrict__ bias,
    const float* __restrict__ gamma, const float* __restrict__ beta,
    const int* __restrict__ cand, const float* __restrict__ emb,
    float* __restrict__ out) {
    __shared__ float4 rowv4[192];  // 768 floats, 16B aligned
    __shared__ float reds[4], redq[4], stat[2];
    float* row = (float*)rowv4;
    const int bp = blockIdx.x;
    const int tid = threadIdx.x, lane = tid & 63, wv = tid >> 6;

    float s = 0.f, qq = 0.f;
    float v[3];
#pragma unroll
    for (int i = 0; i < 3; ++i) {
        const int idx = tid + i * 256;
        const float x = lm[(size_t)bp * EE + idx] + bias[idx];
        v[i] = x; s += x; qq += x * x;
    }
#pragma unroll
    for (int m = 32; m; m >>= 1) { s += __shfl_xor(s, m); qq += __shfl_xor(qq, m); }
    if (lane == 0) { reds[wv] = s; redq[wv] = qq; }
    __syncthreads();
    if (tid == 0) {
        const float S = reds[0] + reds[1] + reds[2] + reds[3];
        const float Q = redq[0] + redq[1] + redq[2] + redq[3];
        const float mu = S * (1.0f / 768.0f);
        const float var = Q * (1.0f / 768.0f) - mu * mu;
        stat[0] = mu; stat[1] = rsqrtf(var + 1e-12f);
    }
    __syncthreads();
    const float mu = stat[0], rstd = stat[1];
#pragma unroll
    for (int i = 0; i < 3; ++i) {
        const int idx = tid + i * 256;
        row[idx] = (v[i] - mu) * rstd * gamma[idx] + beta[idx];
    }
    __syncthreads();

    const float4 l0 = rowv4[lane], l1 = rowv4[lane + 64], l2 = rowv4[lane + 128];
    for (int k = wv; k < KCAND; k += 4) {
        const int cid = cand[bp * KCAND + k];
        const float4* er = (const float4*)(emb + (size_t)cid * EE);
        const float4 a = er[lane], b4 = er[lane + 64], c4 = er[lane + 128];
        float t = a.x * l0.x + a.y * l0.y + a.z * l0.z + a.w * l0.w
                + b4.x * l1.x + b4.y * l1.y + b4.z * l1.z + b4.w * l1.w
                + c4.x * l2.x + c4.y * l2.y + c4.z * l2.z + c4.w * l2.w;
#pragma unroll
        for (int m = 32; m; m >>= 1) t += __shfl_xor(t, m);
        if (lane == 0) out[bp * KCAND + k] = t;
    }
}

extern "C" void kernel_launch(void* const* d_in, const int* in_sizes, int n_in,
                              void* d_out, int out_size, void* d_ws, size_t ws_size,
                              hipStream_t stream) {
    const float* seq   = (const float*)d_in[0];
    const int*   mpos  = (const int*)d_in[1];
    const int*   cand  = (const int*)d_in[2];
    const float* emb   = (const float*)d_in[3];
    const float* W     = (const float*)d_in[4];
    const float* bias  = (const float*)d_in[5];
    const float* gamma = (const float*)d_in[6];
    const float* beta  = (const float*)d_in[7];
    float* out = (float*)d_out;

    // ws layout: Wt (bf16, 768*768*2 = 1,179,648 B = 288 pages) | lm (fp32, 7,471,104 B)
    unsigned short* Wt = (unsigned short*)d_ws;
    float* lm = (float*)((char*)d_ws + 1179648);

    prep_w_kernel<<<dim3(24, 24), 256, 0, stream>>>(W, Wt);
    gemm_kernel<<<dim3(12, 38), 256, 0, stream>>>(seq, mpos, Wt, lm);
    logits_kernel<<<MM, 256, 0, stream>>>(lm, bias, gamma, beta, cand, emb, out);
}

// Round 2
// 292.232 us; speedup vs baseline: 1.0378x; 1.0378x over previous
//
#include <hip/hip_runtime.h>

typedef __attribute__((ext_vector_type(8))) short bf16x8;
typedef __attribute__((ext_vector_type(4))) float f32x4;

#define HH 768   // hidden
#define EE 768   // embed
#define BB 32
#define SS 512
#define PP 76
#define KCAND 64
#define MM (BB * PP)  // 2432

// round-to-nearest-even fp32 -> bf16 bit pattern
__device__ inline unsigned short f2bf(float f) {
    unsigned int u = __float_as_uint(f);
    u += 0x7fffu + ((u >> 16) & 1u);
    return (unsigned short)(u >> 16);
}

// Pass 0 (fused): blocks [0,576) transpose+convert W -> Wt[e][h] bf16;
// blocks [576,880) gather masked rows + convert -> Ag[m][k] bf16.
__global__ __launch_bounds__(256) void prep_kernel(
    const float* __restrict__ W, unsigned short* __restrict__ Wt,
    const float* __restrict__ seq, const int* __restrict__ mpos,
    unsigned short* __restrict__ Ag) {
    const int bid = blockIdx.x;
    if (bid < 576) {
        __shared__ float tile[32][33];
        const int h0 = (bid % 24) * 32, e0 = (bid / 24) * 32;
        const int c = threadIdx.x & 31, r = threadIdx.x >> 5;  // r: 0..7
#pragma unroll
        for (int rr = r; rr < 32; rr += 8)
            tile[rr][c] = W[(size_t)(h0 + rr) * EE + e0 + c];
        __syncthreads();
#pragma unroll
        for (int rr = r; rr < 32; rr += 8)
            Wt[(size_t)(e0 + rr) * HH + h0 + c] = f2bf(tile[c][rr]);
    } else {
        const int m0 = (bid - 576) * 8;
        const int t = threadIdx.x;
#pragma unroll
        for (int rr = 0; rr < 8; ++rr) {
            const int m = m0 + rr;
            const int b = m / PP, p = m - b * PP;
            const int ps = mpos[b * PP + p];
            const float* srow = seq + (size_t)(b * SS + ps) * HH;
            unsigned short* drow = Ag + (size_t)m * HH;
#pragma unroll
            for (int j = 0; j < 3; ++j) {
                const int idx = t + j * 256;
                drow[idx] = f2bf(srow[idx]);
            }
        }
    }
}

// Pass 1: lm_raw[m][e] = sum_h Ag[m][h] * Wt[e][h]  (both bf16, [row][k])
// Tile 64x64, BK=128, pure 16B staging copies, 2x2 waves of 32x32.
__global__ __launch_bounds__(256) void gemm_kernel(
    const unsigned short* __restrict__ Ag, const unsigned short* __restrict__ Wt,
    float* __restrict__ lm) {
    // 136 = 128 + 8 ushort pad: keeps 16B alignment; row stride 272B -> 2-way
    // bank alias at 8 rows apart (free per m136)
    __shared__ unsigned short Alds[64][136];
    __shared__ unsigned short Blds[64][136];
    const int bm = blockIdx.y, bn = blockIdx.x;
    const int tid = threadIdx.x;
    const int sr = tid >> 4;            // staging row within round: 0..15
    const int sc = (tid & 15) * 8;      // ushort col offset (16B chunks)
    const unsigned short* abase = Ag + (size_t)(bm * 64) * HH;
    const unsigned short* bbase = Wt + (size_t)(bn * 64) * HH;

    const int lane = tid & 63, wv = tid >> 6;
    const int wm = wv >> 1, wn = wv & 1;
    const int fr = lane & 15, fq = (lane >> 4) * 8;
    f32x4 acc[2][2] = {};

    for (int kk = 0; kk < HH; kk += 128) {
        __syncthreads();
#pragma unroll
        for (int rnd = 0; rnd < 4; ++rnd) {
            const int row = sr + rnd * 16;
            *(int4*)&Alds[row][sc] = *(const int4*)(abase + (size_t)row * HH + kk + sc);
            *(int4*)&Blds[row][sc] = *(const int4*)(bbase + (size_t)row * HH + kk + sc);
        }
        __syncthreads();
#pragma unroll
        for (int ks = 0; ks < 128; ks += 32) {
            bf16x8 af[2], bfr[2];
#pragma unroll
            for (int t = 0; t < 2; ++t)
                af[t] = *(const bf16x8*)&Alds[wm * 32 + t * 16 + fr][ks + fq];
#pragma unroll
            for (int t = 0; t < 2; ++t)
                bfr[t] = *(const bf16x8*)&Blds[wn * 32 + t * 16 + fr][ks + fq];
#pragma unroll
            for (int tm = 0; tm < 2; ++tm)
#pragma unroll
                for (int tn = 0; tn < 2; ++tn)
                    acc[tm][tn] = __builtin_amdgcn_mfma_f32_16x16x32_bf16(
                        af[tm], bfr[tn], acc[tm][tn], 0, 0, 0);
        }
    }
    // C/D layout: col=lane&15, row=(lane>>4)*4+reg  [verified m89/m91]
#pragma unroll
    for (int tm = 0; tm < 2; ++tm)
#pragma unroll
        for (int tn = 0; tn < 2; ++tn) {
            const int col = bn * 64 + wn * 32 + tn * 16 + (lane & 15);
            const int rbase = bm * 64 + wm * 32 + tm * 16 + (lane >> 4) * 4;
#pragma unroll
            for (int g = 0; g < 4; ++g)
                lm[(size_t)(rbase + g) * EE + col] = acc[tm][tn][g];
        }
}

// Pass 2: bias + LayerNorm (fused) + candidate dot products.
// One block per (b,p); each wave handles 16 candidates, 4 at a time for MLP.
__global__ __launch_bounds__(256) void logits_kernel(
    const float* __restrict__ lm, const float* __restrict__ bias,
    const float* __restrict__ gamma, const float* __restrict__ beta,
    const int* __restrict__ cand, const float* __restrict__ emb,
    float* __restrict__ out) {
    __shared__ float4 rowv4[192];  // 768 floats, 16B aligned
    __shared__ float reds[4], redq[4], stat[2];
    float* row = (float*)rowv4;
    const int bp = blockIdx.x;
    const int tid = threadIdx.x, lane = tid & 63, wv = tid >> 6;

    float s = 0.f, qq = 0.f;
    float v[3];
#pragma unroll
    for (int i = 0; i < 3; ++i) {
        const int idx = tid + i * 256;
        const float x = lm[(size_t)bp * EE + idx] + bias[idx];
        v[i] = x; s += x; qq += x * x;
    }
#pragma unroll
    for (int m = 32; m; m >>= 1) { s += __shfl_xor(s, m); qq += __shfl_xor(qq, m); }
    if (lane == 0) { reds[wv] = s; redq[wv] = qq; }
    __syncthreads();
    if (tid == 0) {
        const float S = reds[0] + reds[1] + reds[2] + reds[3];
        const float Q = redq[0] + redq[1] + redq[2] + redq[3];
        const float mu = S * (1.0f / 768.0f);
        const float var = Q * (1.0f / 768.0f) - mu * mu;
        stat[0] = mu; stat[1] = rsqrtf(var + 1e-12f);
    }
    __syncthreads();
    const float mu = stat[0], rstd = stat[1];
#pragma unroll
    for (int i = 0; i < 3; ++i) {
        const int idx = tid + i * 256;
        row[idx] = (v[i] - mu) * rstd * gamma[idx] + beta[idx];
    }
    __syncthreads();

    const float4 l0 = rowv4[lane], l1 = rowv4[lane + 64], l2 = rowv4[lane + 128];
#pragma unroll
    for (int it = 0; it < 4; ++it) {
        const int k0 = wv * 16 + it * 4;
        const float4* er[4];
#pragma unroll
        for (int c = 0; c < 4; ++c) {
            const int cid = cand[bp * KCAND + k0 + c];
            er[c] = (const float4*)(emb + (size_t)cid * EE);
        }
        float4 ra[4], rb[4], rc[4];
#pragma unroll
        for (int c = 0; c < 4; ++c) {
            ra[c] = er[c][lane]; rb[c] = er[c][lane + 64]; rc[c] = er[c][lane + 128];
        }
        float t[4];
#pragma unroll
        for (int c = 0; c < 4; ++c)
            t[c] = ra[c].x * l0.x + ra[c].y * l0.y + ra[c].z * l0.z + ra[c].w * l0.w
                 + rb[c].x * l1.x + rb[c].y * l1.y + rb[c].z * l1.z + rb[c].w * l1.w
                 + rc[c].x * l2.x + rc[c].y * l2.y + rc[c].z * l2.z + rc[c].w * l2.w;
#pragma unroll
        for (int m = 32; m; m >>= 1) {
#pragma unroll
            for (int c = 0; c < 4; ++c) t[c] += __shfl_xor(t[c], m);
        }
        if (lane == 0) {
#pragma unroll
            for (int c = 0; c < 4; ++c) out[bp * KCAND + k0 + c] = t[c];
        }
    }
}

extern "C" void kernel_launch(void* const* d_in, const int* in_sizes, int n_in,
                              void* d_out, int out_size, void* d_ws, size_t ws_size,
                              hipStream_t stream) {
    const float* seq   = (const float*)d_in[0];
    const int*   mpos  = (const int*)d_in[1];
    const int*   cand  = (const int*)d_in[2];
    const float* emb   = (const float*)d_in[3];
    const float* W     = (const float*)d_in[4];
    const float* bias  = (const float*)d_in[5];
    const float* gamma = (const float*)d_in[6];
    const float* beta  = (const float*)d_in[7];
    float* out = (float*)d_out;

    // ws: Wt bf16 (1,179,648 B) | Ag bf16 (3,735,552 B) | lm fp32 (7,471,104 B)
    unsigned short* Wt = (unsigned short*)d_ws;
    unsigned short* Ag = (unsigned short*)((char*)d_ws + 1179648);
    float* lm = (float*)((char*)d_ws + 1179648 + 3735552);

    prep_kernel<<<880, 256, 0, stream>>>(W, Wt, seq, mpos, Ag);
    gemm_kernel<<<dim3(12, 38), 256, 0, stream>>>(Ag, Wt, lm);
    logits_kernel<<<MM, 256, 0, stream>>>(lm, bias, gamma, beta, cand, emb, out);
}